// Round 1
// baseline (4634.609 us; speedup 1.0000x reference)
//
#include <hip/hip_runtime.h>
#include <math.h>

#define Bz 32
#define Tz 20
#define TMz 19
#define Hz 256
#define Ez 512
#define Vz 10000
#define Dz 256
#define Pz 1024
#define INFLAT 262144   // P*D
#define RELSZ 16384
#define LINz 1024       // E + D + H

__device__ __forceinline__ float sigm(float x) { return 1.0f / (1.0f + expf(-x)); }

// ---------------- sort: stable argsort of -lens ----------------
__global__ void k_sort(const int* __restrict__ lens, float* __restrict__ out_order,
                       int* __restrict__ ord, int* __restrict__ sentlen) {
    if (threadIdx.x == 0 && blockIdx.x == 0) {
        int l[Bz]; bool used[Bz];
        for (int b = 0; b < Bz; ++b) { l[b] = lens[b]; used[b] = false; }
        for (int i = 0; i < Bz; ++i) {
            int best = -1;
            for (int j = 0; j < Bz; ++j)
                if (!used[j] && (best < 0 || l[j] > l[best])) best = j;
            used[best] = true;
            ord[i] = best;
            sentlen[i] = l[best] - 1;
            out_order[i] = (float)best;
        }
    }
}

// ---------------- h0,c0: flat(32,262144) @ W_ih / W_ic, split-K ----------------
// grid 512, block 256. chunk KCH=512. partials p[(chunk*32+b)*256+j]
__global__ __launch_bounds__(256) void k_gemv2(const float* __restrict__ X, const int* __restrict__ ord,
                                               const float* __restrict__ W1, const float* __restrict__ W2,
                                               float* __restrict__ p1, float* __restrict__ p2) {
    __shared__ float xs[32 * 512];   // 64 KB
    __shared__ int ords[32];
    int tid = threadIdx.x, bx = blockIdx.x;
    if (tid < 32) ords[tid] = ord[tid];
    __syncthreads();
    size_t k0 = (size_t)bx * 512;
    for (int idx = tid; idx < 32 * 512; idx += 256) {
        int b = idx >> 9, kk = idx & 511;
        xs[idx] = X[(size_t)ords[b] * INFLAT + k0 + kk];
    }
    __syncthreads();
    float ah[32], ac[32];
#pragma unroll
    for (int b = 0; b < 32; ++b) { ah[b] = 0.f; ac[b] = 0.f; }
    for (int kk = 0; kk < 512; ++kk) {
        size_t w_off = (k0 + kk) * 256 + tid;
        float w1 = W1[w_off], w2 = W2[w_off];
#pragma unroll
        for (int b = 0; b < 32; ++b) {
            float xv = xs[b * 512 + kk];
            ah[b] += xv * w1;
            ac[b] += xv * w2;
        }
    }
#pragma unroll
    for (int b = 0; b < 32; ++b) {
        size_t o = ((size_t)bx * 32 + b) * 256 + tid;
        p1[o] = ah[b];
        p2[o] = ac[b];
    }
}

// ---------------- C0: rel(32,16384) @ W_iC, split-K ----------------
// grid 128, block 256, KCH=128
__global__ __launch_bounds__(256) void k_gemvC(const float* __restrict__ R, const int* __restrict__ ord,
                                               const float* __restrict__ W, float* __restrict__ p) {
    __shared__ float xs[32 * 128];
    __shared__ int ords[32];
    int tid = threadIdx.x, bx = blockIdx.x;
    if (tid < 32) ords[tid] = ord[tid];
    __syncthreads();
    int k0 = bx * 128;
    for (int idx = tid; idx < 32 * 128; idx += 256) {
        int b = idx >> 7, kk = idx & 127;
        xs[idx] = R[(size_t)ords[b] * RELSZ + k0 + kk];
    }
    __syncthreads();
    float acc[32];
#pragma unroll
    for (int b = 0; b < 32; ++b) acc[b] = 0.f;
    for (int kk = 0; kk < 128; ++kk) {
        float w = W[(size_t)(k0 + kk) * 256 + tid];
#pragma unroll
        for (int b = 0; b < 32; ++b) acc[b] += xs[b * 128 + kk] * w;
    }
#pragma unroll
    for (int b = 0; b < 32; ++b) p[((size_t)bx * 32 + b) * 256 + tid] = acc[b];
}

// ---------------- split-K reduce + bias. grid 32(b), block 256(j) ----------------
__global__ __launch_bounds__(256) void k_reduce(const float* __restrict__ p, int nch,
                                                const float* __restrict__ bias, float* __restrict__ out) {
    int b = blockIdx.x, j = threadIdx.x;
    float s = bias[j];
    for (int c = 0; c < nch; ++c) s += p[((size_t)c * 32 + b) * 256 + j];
    out[b * 256 + j] = s;
}

// ---------------- att1 = info_sorted @ W_enc + b_enc ----------------
// grid 1024 (32 rows each), block 256
__global__ __launch_bounds__(256) void k_att1(const float* __restrict__ info, const int* __restrict__ ord,
                                              const float* __restrict__ W, const float* __restrict__ bias,
                                              float* __restrict__ att1) {
    __shared__ float xs[32 * 256];   // 32 KB
    int tid = threadIdx.x;
    int r0 = blockIdx.x * 32;
    int b = r0 >> 10, p0 = r0 & 1023;
    int ordb = ord[b];
    const float* src = info + (size_t)ordb * INFLAT + (size_t)p0 * 256;
    for (int idx = tid; idx < 32 * 256; idx += 256) xs[idx] = src[idx];
    __syncthreads();
    float acc[32];
#pragma unroll
    for (int r = 0; r < 32; ++r) acc[r] = 0.f;
    for (int k = 0; k < 256; ++k) {
        float w = W[k * 256 + tid];
#pragma unroll
        for (int r = 0; r < 32; ++r) acc[r] += xs[r * 256 + k] * w;
    }
    float bj = bias[tid];
#pragma unroll
    for (int r = 0; r < 32; ++r) att1[((size_t)(r0 + r)) * 256 + tid] = acc[r] + bj;
}

// ---------------- step: att2 + e + exp(e) + Z partials ----------------
// grid 256: b = bx>>3, pc = bx&7 (128 p-rows). block 256.
__global__ __launch_bounds__(256) void k_step_e(const float* __restrict__ att1, const float* __restrict__ hst,
                                                const float* __restrict__ W_dec, const float* __restrict__ b_dec,
                                                const float* __restrict__ W_full, const float* __restrict__ b_full,
                                                float* __restrict__ expe, float* __restrict__ zpart) {
    __shared__ float hs[256], at2[256], wf[256], zs[4];
    int tid = threadIdx.x;
    int b = blockIdx.x >> 3, pc = blockIdx.x & 7;
    hs[tid] = hst[b * 256 + tid];
    wf[tid] = W_full[tid];
    float bfull = b_full[0];
    __syncthreads();
    float a = b_dec[tid];
    for (int k = 0; k < 256; ++k) a += hs[k] * W_dec[k * 256 + tid];
    at2[tid] = a;
    __syncthreads();
    int wave = tid >> 6, lane = tid & 63;
    float zacc = 0.f;
    for (int i = 0; i < 32; ++i) {
        int p = pc * 128 + wave * 32 + i;
        const float* row = att1 + ((size_t)(b * 1024 + p)) * 256;
        float s = 0.f;
#pragma unroll
        for (int m = 0; m < 4; ++m) {
            int k = lane + 64 * m;
            float v = row[k] + at2[k];
            v = fmaxf(v, 0.f);
            s += v * wf[k];
        }
        for (int off = 32; off > 0; off >>= 1) s += __shfl_down(s, off);
        if (lane == 0) {
            float ex = expf(s + bfull);
            expe[b * 1024 + p] = ex;
            zacc += ex;
        }
    }
    if (lane == 0) zs[wave] = zacc;
    __syncthreads();
    if (tid == 0) zpart[b * 8 + pc] = zs[0] + zs[1] + zs[2] + zs[3];
}

// ---------------- step: awf partials (incl 1/Z) + alpha output ----------------
// grid 256: b = bx>>3, pc = bx&7. block 256 (d)
__global__ __launch_bounds__(256) void k_step_awf(const float* __restrict__ info, const int* __restrict__ ord,
                                                  const float* __restrict__ expe, const float* __restrict__ zpart,
                                                  float* __restrict__ awfp, float* __restrict__ out_alpha,
                                                  const int* __restrict__ sentlen, int t) {
    int tid = threadIdx.x;
    int b = blockIdx.x >> 3, pc = blockIdx.x & 7;
    float Z = 0.f;
    for (int c = 0; c < 8; ++c) Z += zpart[b * 8 + c];
    float invZ = 1.0f / Z;
    int ordb = ord[b];
    const float* base = info + (size_t)ordb * INFLAT + (size_t)(pc * 128) * 256;
    const float* ebase = expe + b * 1024 + pc * 128;
    float acc = 0.f;
    for (int i = 0; i < 128; ++i) acc += ebase[i] * base[(size_t)i * 256 + tid];
    awfp[((size_t)(b * 8 + pc)) * 256 + tid] = acc * invZ;
    float m = (sentlen[b] > t) ? invZ : 0.0f;
    if (tid < 128) {
        int p = pc * 128 + tid;
        out_alpha[((size_t)(b * TMz + t)) * 1024 + p] = expe[b * 1024 + p] * m;
    }
}

// ---------------- step: gate partials (builds x chunk in-block) ----------------
// grid 40: g = bx/8, kc = bx%8 (k-chunk 128). block 256 (j)
__global__ __launch_bounds__(256) void k_step_gates(const int* __restrict__ caps, const int* __restrict__ ord,
                                                    const float* __restrict__ emb, const float* __restrict__ awfp,
                                                    const float* __restrict__ hst,
                                                    const float* __restrict__ W_i, const float* __restrict__ W_f,
                                                    const float* __restrict__ W_o, const float* __restrict__ W_g1,
                                                    const float* __restrict__ W_g2,
                                                    float* __restrict__ gpart, int t) {
    __shared__ float xs[32 * 128];   // 16 KB
    int tid = threadIdx.x;
    int g = blockIdx.x >> 3, kc = blockIdx.x & 7;
    int k0 = kc * 128;
    const float* Wg = (g == 0) ? W_i : (g == 1) ? W_f : (g == 2) ? W_o : (g == 3) ? W_g1 : W_g2;
    for (int idx = tid; idx < 32 * 128; idx += 256) {
        int b = idx >> 7, kk = idx & 127;
        int k = k0 + kk;
        float v;
        if (k < 512) {
            int cap = caps[ord[b] * Tz + t];
            v = emb[(size_t)cap * Ez + k];
        } else if (k < 768) {
            int d = k - 512;
            float s = 0.f;
            for (int c = 0; c < 8; ++c) s += awfp[((size_t)(b * 8 + c)) * 256 + d];
            v = s;
        } else {
            v = hst[b * 256 + (k - 768)];
        }
        xs[idx] = v;
    }
    __syncthreads();
    float acc[32];
#pragma unroll
    for (int b = 0; b < 32; ++b) acc[b] = 0.f;
    for (int kk = 0; kk < 128; ++kk) {
        float w = Wg[(size_t)(k0 + kk) * 256 + tid];
#pragma unroll
        for (int b = 0; b < 32; ++b) acc[b] += xs[b * 128 + kk] * w;
    }
#pragma unroll
    for (int b = 0; b < 32; ++b)
        gpart[((size_t)((g * 8 + kc) * 32 + b)) * 256 + tid] = acc[b];
}

// ---------------- step: cell update (new c, new C) + mlp partials ----------------
// grid 8 (kc over 512 cc-cols, 64 each). block 256 (j)
__global__ __launch_bounds__(256) void k_step_cell(const float* __restrict__ gpart,
                                                   const float* __restrict__ b_i, const float* __restrict__ b_f,
                                                   const float* __restrict__ b_g1, const float* __restrict__ b_g2,
                                                   float* __restrict__ cst, float* __restrict__ Cst,
                                                   const float* __restrict__ W_mlp, float* __restrict__ mlppart) {
    __shared__ float ccs[32 * 64];   // 8 KB
    int tid = threadIdx.x;
    int kc = blockIdx.x;
    int k0 = kc * 64;
    for (int idx = tid; idx < 32 * 64; idx += 256) {
        int b = idx >> 6, kk = idx & 63;
        int k = k0 + kk;
        int isC = (k >= 256);
        int j = isC ? (k - 256) : k;
        float iv = b_i[j], fv = b_f[j];
        float gv = isC ? b_g2[j] : b_g1[j];
        int gi = isC ? 4 : 3;
        for (int c = 0; c < 8; ++c) {
            iv += gpart[((size_t)((0 * 8 + c) * 32 + b)) * 256 + j];
            fv += gpart[((size_t)((1 * 8 + c) * 32 + b)) * 256 + j];
            gv += gpart[((size_t)((gi * 8 + c) * 32 + b)) * 256 + j];
        }
        iv = sigm(iv);
        fv = sigm(fv);
        gv = tanhf(gv);
        float old = isC ? Cst[b * 256 + j] : cst[b * 256 + j];
        float nv = fv * old + iv * gv;
        if (isC) Cst[b * 256 + j] = nv; else cst[b * 256 + j] = nv;
        ccs[idx] = nv;
    }
    __syncthreads();
    float macc[32];
#pragma unroll
    for (int b = 0; b < 32; ++b) macc[b] = 0.f;
    for (int kk = 0; kk < 64; ++kk) {
        float w = W_mlp[(size_t)(k0 + kk) * 256 + tid];
#pragma unroll
        for (int b = 0; b < 32; ++b) macc[b] += ccs[b * 64 + kk] * w;
    }
#pragma unroll
    for (int b = 0; b < 32; ++b) mlppart[((size_t)(kc * 32 + b)) * 256 + tid] = macc[b];
}

// ---------------- step: h = o * tanh(mlp) ----------------
// grid 32 (b), block 256 (j)
__global__ __launch_bounds__(256) void k_step_h(const float* __restrict__ gpart, const float* __restrict__ b_o,
                                                const float* __restrict__ mlppart, const float* __restrict__ b_mlp,
                                                float* __restrict__ hst) {
    int b = blockIdx.x, j = threadIdx.x;
    float o = b_o[j];
    for (int c = 0; c < 8; ++c) o += gpart[((size_t)((2 * 8 + c) * 32 + b)) * 256 + j];
    o = sigm(o);
    float m = b_mlp[j];
    for (int kc = 0; kc < 8; ++kc) m += mlppart[((size_t)(kc * 32 + b)) * 256 + j];
    hst[b * 256 + j] = o * tanhf(m);
}

// ---------------- step: pred = h @ W_fc + b_fc (masked) ----------------
// grid 40 (v-tiles of 256), block 256
__global__ __launch_bounds__(256) void k_step_pred(const float* __restrict__ hst, const float* __restrict__ W_fc,
                                                   const float* __restrict__ b_fc, const int* __restrict__ sentlen,
                                                   float* __restrict__ out_pred, int t) {
    __shared__ float hs[32 * 256];   // 32 KB
    int tid = threadIdx.x;
    for (int idx = tid; idx < 32 * 256; idx += 256) hs[idx] = hst[idx];
    __syncthreads();
    int v = blockIdx.x * 256 + tid;
    float acc[32];
#pragma unroll
    for (int b = 0; b < 32; ++b) acc[b] = 0.f;
    if (v < Vz) {
        for (int j = 0; j < 256; ++j) {
            float w = W_fc[(size_t)j * Vz + v];
#pragma unroll
            for (int b = 0; b < 32; ++b) acc[b] += hs[b * 256 + j] * w;
        }
        float bv = b_fc[v];
#pragma unroll
        for (int b = 0; b < 32; ++b) {
            float r = (sentlen[b] > t) ? (acc[b] + bv) : 0.0f;
            out_pred[((size_t)(b * TMz + t)) * Vz + v] = r;
        }
    }
}

extern "C" void kernel_launch(void* const* d_in, const int* in_sizes, int n_in,
                              void* d_out, int out_size, void* d_ws, size_t ws_size,
                              hipStream_t stream) {
    const float* info  = (const float*)d_in[0];
    const float* rel   = (const float*)d_in[1];
    const int*   caps  = (const int*)d_in[2];
    const int*   lens  = (const int*)d_in[3];
    const float* emb   = (const float*)d_in[4];
    const float* W_enc = (const float*)d_in[5];
    const float* b_enc = (const float*)d_in[6];
    const float* W_dec = (const float*)d_in[7];
    const float* b_dec = (const float*)d_in[8];
    const float* W_full= (const float*)d_in[9];
    const float* b_full= (const float*)d_in[10];
    const float* W_i   = (const float*)d_in[11];
    const float* b_i   = (const float*)d_in[12];
    const float* W_f   = (const float*)d_in[13];
    const float* b_f   = (const float*)d_in[14];
    const float* W_o   = (const float*)d_in[15];
    const float* b_o   = (const float*)d_in[16];
    const float* W_g1  = (const float*)d_in[17];
    const float* b_g1  = (const float*)d_in[18];
    const float* W_g2  = (const float*)d_in[19];
    const float* b_g2  = (const float*)d_in[20];
    const float* W_mlp = (const float*)d_in[21];
    const float* b_mlp = (const float*)d_in[22];
    // 23,24 = W_beta,b_beta unused
    const float* W_fc  = (const float*)d_in[25];
    const float* b_fc  = (const float*)d_in[26];
    const float* W_ih  = (const float*)d_in[27];
    const float* b_ih  = (const float*)d_in[28];
    const float* W_ic  = (const float*)d_in[29];
    const float* b_ic  = (const float*)d_in[30];
    const float* W_iC  = (const float*)d_in[31];
    const float* b_iC  = (const float*)d_in[32];

    float* out = (float*)d_out;
    float* out_pred  = out;                                  // 32*19*10000
    float* out_alpha = out + (size_t)Bz * TMz * Vz;          // 32*19*1024
    float* out_order = out_alpha + (size_t)Bz * TMz * Pz;    // 32

    float* w = (float*)d_ws;
    float* att1    = w;                          // 8,388,608 floats (also split-K partial space in phase A)
    float* ph      = w;                          // 512*32*256 = 4,194,304
    float* pcpart  = w + 4194304;                // 4,194,304
    float* expe    = w + 8388608;                // 32768
    float* zpart   = w + 8421376;                // 256
    float* awfp    = w + 8421632;                // 65536
    float* gpart   = w + 8487168;                // 327680
    float* mlppart = w + 8814848;                // 65536
    float* hst     = w + 8880384;                // 8192
    float* cst     = w + 8888576;                // 8192
    float* Cst     = w + 8896768;                // 8192
    int*   ordp    = (int*)(w + 8904960);        // 32 ints
    int*   slp     = ordp + 32;                  // 32 ints
    float* pC      = w + 8905024;                // 128*32*256 = 1,048,576

    // ---- phase A ----
    k_sort<<<1, 64, 0, stream>>>(lens, out_order, ordp, slp);
    k_gemv2<<<512, 256, 0, stream>>>(info, ordp, W_ih, W_ic, ph, pcpart);
    k_reduce<<<32, 256, 0, stream>>>(ph, 512, b_ih, hst);
    k_reduce<<<32, 256, 0, stream>>>(pcpart, 512, b_ic, cst);
    k_gemvC<<<128, 256, 0, stream>>>(rel, ordp, W_iC, pC);
    k_reduce<<<32, 256, 0, stream>>>(pC, 128, b_iC, Cst);
    k_att1<<<1024, 256, 0, stream>>>(info, ordp, W_enc, b_enc, att1);

    // ---- sequential steps ----
    for (int t = 0; t < TMz; ++t) {
        k_step_e<<<256, 256, 0, stream>>>(att1, hst, W_dec, b_dec, W_full, b_full, expe, zpart);
        k_step_awf<<<256, 256, 0, stream>>>(info, ordp, expe, zpart, awfp, out_alpha, slp, t);
        k_step_gates<<<40, 256, 0, stream>>>(caps, ordp, emb, awfp, hst,
                                             W_i, W_f, W_o, W_g1, W_g2, gpart, t);
        k_step_cell<<<8, 256, 0, stream>>>(gpart, b_i, b_f, b_g1, b_g2, cst, Cst, W_mlp, mlppart);
        k_step_h<<<32, 256, 0, stream>>>(gpart, b_o, mlppart, b_mlp, hst);
        k_step_pred<<<40, 256, 0, stream>>>(hst, W_fc, b_fc, slp, out_pred, t);
    }
}